// Round 1
// baseline (4886.802 us; speedup 1.0000x reference)
//
#include <hip/hip_runtime.h>
#include <math.h>

// ---------------------------------------------------------------------------
// Stacked vanilla RNN (2 layers), SEQ=128 B=64 E=512 H=1024 V=10000.
// Strategy:
//   prep:   transpose+split all weights to bf16 hi/lo in [n][k] layout;
//           gather x = emb[tok]*sqrt(E) as bf16 hi/lo; cast initial hidden.
//   XP0 = x @ W_x0 + b0          (3-pass split-bf16 MFMA GEMM, f32 out)
//   recur L0: 128 serial steps h0[t]=tanh(XP0[t]+h0[t-1]@Wh0)  (grid barrier/step)
//   XP1 = H0 @ W_x1 + b1         (3-pass GEMM)
//   recur L1: 128 serial steps
//   logits = H1 @ W_out + b_out  (1-pass bf16 GEMM, supertiled for L2)
// ---------------------------------------------------------------------------

typedef unsigned short u16;
typedef __bf16 bf16x8 __attribute__((ext_vector_type(8)));
typedef float  f32x4  __attribute__((ext_vector_type(4)));
typedef unsigned int u32x4 __attribute__((ext_vector_type(4)));
typedef u16 u16x8 __attribute__((ext_vector_type(8)));

#define SEQ_ 128
#define B_   64
#define E_   512
#define H_   1024
#define V_   10000
#define VP_  10112           // V padded to multiple of 128 for GEMM tiles
#define ROWS_ (SEQ_*B_)      // 8192
#define LOGITS_ 81920000     // SEQ*B*V

__device__ __forceinline__ u16 f2bf(float f) {          // RNE f32 -> bf16
  unsigned u = __builtin_bit_cast(unsigned, f);
  u += 0x7fffu + ((u >> 16) & 1u);
  return (u16)(u >> 16);
}
__device__ __forceinline__ float bf2f(u16 h) {
  unsigned u = ((unsigned)h) << 16;
  return __builtin_bit_cast(float, u);
}

// --------------------------- prep kernels ----------------------------------

// in: f32 [K][N] row-major  ->  out: bf16 [NP][K] (transposed), hi + optional lo.
// Rows n in [N, NP) are written as zeros (padding for GEMM tiles).
__global__ __launch_bounds__(256)
void transpose_split(const float* __restrict__ in, u16* __restrict__ outHi,
                     u16* __restrict__ outLo, int K, int N, int NP)
{
  __shared__ float tile[32][33];
  const int n0 = blockIdx.x * 32, k0 = blockIdx.y * 32;
  const int x = threadIdx.x & 31;
  const int y = threadIdx.x >> 5;
  (void)NP;
#pragma unroll
  for (int i = 0; i < 4; ++i) {
    const int r = y * 4 + i;
    const int n = n0 + x;
    tile[r][x] = (n < N) ? in[(size_t)(k0 + r) * N + n] : 0.f;
  }
  __syncthreads();
#pragma unroll
  for (int i = 0; i < 4; ++i) {
    const int r = y * 4 + i;
    const int n = n0 + r;
    const int k = k0 + x;
    const float v = tile[x][r];
    const u16 hb = f2bf(v);
    outHi[(size_t)n * K + k] = hb;
    if (outLo) outLo[(size_t)n * K + k] = f2bf(v - bf2f(hb));
  }
}

// x[row][c] = emb[tok[row]][c] * sqrt(E), split hi/lo.  row = t*64+b.
__global__ __launch_bounds__(256)
void gather_x(const int* __restrict__ toks, const float* __restrict__ emb,
              u16* __restrict__ XBhi, u16* __restrict__ XBlo)
{
  const int tid = blockIdx.x * 256 + threadIdx.x;   // ROWS_*E_/8 threads
  const int row = tid >> 6;
  const int c8 = (tid & 63) * 8;
  const int tok = toks[row];
  const float* e = emb + (size_t)tok * E_ + c8;
  u16x8 hv, lv;
#pragma unroll
  for (int j = 0; j < 8; ++j) {
    float f = e[j] * 22.627416997969522f;            // sqrt(512)
    u16 hb = f2bf(f);
    hv[j] = hb;
    lv[j] = f2bf(f - bf2f(hb));
  }
  *(u16x8*)(XBhi + (size_t)row * E_ + c8) = hv;
  *(u16x8*)(XBlo + (size_t)row * E_ + c8) = lv;
}

// initial hidden (2,64,1024) f32 -> slot 0 of H0 / H1 (hi/lo)
__global__ __launch_bounds__(256)
void hid_cast(const float* __restrict__ h, u16* H0hi, u16* H0lo, u16* H1hi, u16* H1lo)
{
  const int tid = blockIdx.x * 256 + threadIdx.x;   // B_*H_ threads
  float v0 = h[tid], v1 = h[B_ * H_ + tid];
  u16 a = f2bf(v0); H0hi[tid] = a; H0lo[tid] = f2bf(v0 - bf2f(a));
  u16 b = f2bf(v1); H1hi[tid] = b; H1lo[tid] = f2bf(v1 - bf2f(b));
}

// --------------------------- generic MFMA GEMM -----------------------------
// C[M][ldc] (+bias, masked to Nreal) = A[M][K] @ B^T   where B is [NP][K] n-major.
// NPASS==3: A,B given as hi/lo pairs; acc += Ahi*Bhi + Ahi*Blo + Alo*Bhi.
// Tiles: 128x128 per block, BK=32, 4 waves, wave = 64x64 (4x4 16x16 frags).
// 1D grid, supertile decode (S=8 n-blocks per band) for L2 reuse of B.
template<int NPASS>
__global__ __launch_bounds__(256)
void gemm_bf16(const u16* __restrict__ Ahi, const u16* __restrict__ Alo,
               const u16* __restrict__ Bhi, const u16* __restrict__ Blo,
               const float* __restrict__ bias, float* __restrict__ C,
               int K, int Nreal, int ldc, int nbx, int nby)
{
  constexpr int LDT = 40;   // u16 per LDS row (80 B: pad vs 64 B to spread banks)
  __shared__ u16 lds[(NPASS == 3 ? 4 : 2) * 128 * LDT];
  u16* As  = lds;
  u16* Bs  = lds + 128 * LDT;
  u16* As2 = (NPASS == 3) ? (lds + 2 * 128 * LDT) : lds;
  u16* Bs2 = (NPASS == 3) ? (lds + 3 * 128 * LDT) : lds;

  // supertile decode
  const int S = 8;
  int bid  = blockIdx.x;
  int scol = bid / (S * nby);
  int rem  = bid - scol * (S * nby);
  int w    = nbx - scol * S; if (w > S) w = S;
  int bx   = scol * S + rem % w;
  int by   = rem / w;
  const int m0 = by * 128, n0 = bx * 128;

  const int tid  = threadIdx.x;
  const int wave = tid >> 6, lane = tid & 63;
  const int wm = (wave & 1) * 64, wn = (wave >> 1) * 64;
  const int lrow = lane & 15, lk = (lane >> 4) * 8;

  f32x4 acc[4][4] = {};

  const int kTiles = K >> 5;
  for (int kt = 0; kt < kTiles; ++kt) {
    const int k0 = kt << 5;
    __syncthreads();
#pragma unroll
    for (int c = tid; c < 512; c += 256) {
      const int row = c >> 2, kq = c & 3;
      const int l = row * LDT + kq * 8;
      *(u32x4*)(As + l) = *(const u32x4*)(Ahi + (size_t)(m0 + row) * K + k0 + kq * 8);
      *(u32x4*)(Bs + l) = *(const u32x4*)(Bhi + (size_t)(n0 + row) * K + k0 + kq * 8);
      if constexpr (NPASS == 3) {
        *(u32x4*)(As2 + l) = *(const u32x4*)(Alo + (size_t)(m0 + row) * K + k0 + kq * 8);
        *(u32x4*)(Bs2 + l) = *(const u32x4*)(Blo + (size_t)(n0 + row) * K + k0 + kq * 8);
      }
    }
    __syncthreads();
    bf16x8 a[4], b[4];
#pragma unroll
    for (int i = 0; i < 4; ++i) {
      a[i] = *(const bf16x8*)(As + (wm + i * 16 + lrow) * LDT + lk);
      b[i] = *(const bf16x8*)(Bs + (wn + i * 16 + lrow) * LDT + lk);
    }
    if constexpr (NPASS == 3) {
      bf16x8 a2[4], b2[4];
#pragma unroll
      for (int i = 0; i < 4; ++i) {
        a2[i] = *(const bf16x8*)(As2 + (wm + i * 16 + lrow) * LDT + lk);
        b2[i] = *(const bf16x8*)(Bs2 + (wn + i * 16 + lrow) * LDT + lk);
      }
#pragma unroll
      for (int mi = 0; mi < 4; ++mi)
#pragma unroll
        for (int ni = 0; ni < 4; ++ni) {
          acc[mi][ni] = __builtin_amdgcn_mfma_f32_16x16x32_bf16(a[mi],  b[ni],  acc[mi][ni], 0, 0, 0);
          acc[mi][ni] = __builtin_amdgcn_mfma_f32_16x16x32_bf16(a[mi],  b2[ni], acc[mi][ni], 0, 0, 0);
          acc[mi][ni] = __builtin_amdgcn_mfma_f32_16x16x32_bf16(a2[mi], b[ni],  acc[mi][ni], 0, 0, 0);
        }
    } else {
#pragma unroll
      for (int mi = 0; mi < 4; ++mi)
#pragma unroll
        for (int ni = 0; ni < 4; ++ni)
          acc[mi][ni] = __builtin_amdgcn_mfma_f32_16x16x32_bf16(a[mi], b[ni], acc[mi][ni], 0, 0, 0);
    }
  }
  // epilogue: C/D layout col=lane&15, row=(lane>>4)*4+r (m89-verified)
#pragma unroll
  for (int mi = 0; mi < 4; ++mi)
#pragma unroll
    for (int ni = 0; ni < 4; ++ni)
#pragma unroll
      for (int r = 0; r < 4; ++r) {
        const int row = m0 + wm + mi * 16 + (lane >> 4) * 4 + r;
        const int col = n0 + wn + ni * 16 + lrow;
        if (col < Nreal) {
          float v = acc[mi][ni][r];
          if (bias) v += bias[col];
          C[(size_t)row * ldc + col] = v;
        }
      }
}

// --------------------------- grid barrier ----------------------------------
// Flag-array barrier: parallel arrivals (one store per WG), WG0's wave0 scans
// all flags lane-parallel, then publishes a generation counter. Agent-scope
// fences give cross-XCD visibility (G16).
__device__ __forceinline__ void gbar(unsigned* flags, unsigned* gen, unsigned my)
{
  __syncthreads();
  if (blockIdx.x == 0) {
    if (threadIdx.x < 64) {
      const unsigned l = threadIdx.x;
      bool ok = (l == 0) || (l >= gridDim.x);
      for (;;) {
        if (!ok) ok = (__hip_atomic_load(flags + l * 16, __ATOMIC_RELAXED,
                                         __HIP_MEMORY_SCOPE_AGENT) >= my);
        if (__all((int)ok)) break;
        __builtin_amdgcn_s_sleep(1);
      }
      __builtin_amdgcn_fence(__ATOMIC_ACQ_REL, "agent");
      if (l == 0)
        __hip_atomic_store(gen, my, __ATOMIC_RELAXED, __HIP_MEMORY_SCOPE_AGENT);
    }
  } else if (threadIdx.x == 0) {
    __builtin_amdgcn_fence(__ATOMIC_RELEASE, "agent");
    __hip_atomic_store(flags + blockIdx.x * 16, my, __ATOMIC_RELAXED,
                       __HIP_MEMORY_SCOPE_AGENT);
    while (__hip_atomic_load(gen, __ATOMIC_RELAXED, __HIP_MEMORY_SCOPE_AGENT) < my)
      __builtin_amdgcn_s_sleep(1);
    __builtin_amdgcn_fence(__ATOMIC_ACQUIRE, "agent");
  }
  __syncthreads();
}

// --------------------------- recurrence ------------------------------------
// 64 WGs x 4 waves = 256 waves; wave (wg,w) owns output tile
// rows [w*16,w*16+16) x cols [wg*16,wg*16+16) of the 64x1024 hidden state.
// Per step: acc = XP[t] frag; acc += h[t-1] @ Wh (3-pass split-bf16); tanh;
// store h[t] hi/lo; grid barrier.  H slots: slot s holds state before step s.
__global__ __launch_bounds__(256, 1)
void recur_layer(const u16* __restrict__ Whi, const u16* __restrict__ Wlo,
                 const float* __restrict__ XP,
                 u16* __restrict__ Hhi, u16* __restrict__ Hlo,
                 float* __restrict__ finalH,
                 unsigned* flags, unsigned* gen)
{
  const int w    = threadIdx.x >> 6;
  const int lane = threadIdx.x & 63;
  const int nt   = blockIdx.x;            // n-tile 0..63
  const int lrow = lane & 15, lkg = lane >> 4;
  const int crow = lkg * 4;
  const u16* Bh = Whi + (size_t)(nt * 16 + lrow) * H_ + lkg * 8;
  const u16* Bl = Wlo + (size_t)(nt * 16 + lrow) * H_ + lkg * 8;
  const int arow = w * 16 + lrow;
  unsigned my = 0;

  for (int t = 0; t < SEQ_; ++t) {
    const size_t hoff = (size_t)t * (B_ * H_);
    const u16* A0 = Hhi + hoff + (size_t)arow * H_ + lkg * 8;
    const u16* A1 = Hlo + hoff + (size_t)arow * H_ + lkg * 8;
    const float* xp = XP + hoff + (size_t)(w * 16 + crow) * H_ + nt * 16 + lrow;
    f32x4 acc = { xp[0], xp[H_], xp[2 * H_], xp[3 * H_] };
#pragma unroll
    for (int kc = 0; kc < 32; ++kc) {
      bf16x8 ah = *(const bf16x8*)(A0 + kc * 32);
      bf16x8 al = *(const bf16x8*)(A1 + kc * 32);
      bf16x8 bh = *(const bf16x8*)(Bh + kc * 32);
      bf16x8 bl = *(const bf16x8*)(Bl + kc * 32);
      acc = __builtin_amdgcn_mfma_f32_16x16x32_bf16(ah, bh, acc, 0, 0, 0);
      acc = __builtin_amdgcn_mfma_f32_16x16x32_bf16(ah, bl, acc, 0, 0, 0);
      acc = __builtin_amdgcn_mfma_f32_16x16x32_bf16(al, bh, acc, 0, 0, 0);
    }
    u16* OH = Hhi + hoff + (B_ * H_);
    u16* OL = Hlo + hoff + (B_ * H_);
#pragma unroll
    for (int r = 0; r < 4; ++r) {
      const int row = w * 16 + crow + r;
      const int col = nt * 16 + lrow;
      float hv = tanhf(acc[r]);
      u16 hb = f2bf(hv);
      OH[(size_t)row * H_ + col] = hb;
      OL[(size_t)row * H_ + col] = f2bf(hv - bf2f(hb));
      if (t == SEQ_ - 1) finalH[(size_t)row * H_ + col] = hv;
    }
    ++my;
    if (t < SEQ_ - 1) gbar(flags, gen, my);
  }
}

// --------------------------- launch ----------------------------------------
extern "C" void kernel_launch(void* const* d_in, const int* in_sizes, int n_in,
                              void* d_out, int out_size, void* d_ws, size_t ws_size,
                              hipStream_t stream)
{
  (void)in_sizes; (void)n_in; (void)out_size; (void)ws_size; // needs ~187 MB ws
  const int*   toks = (const int*)d_in[0];
  const float* hid0 = (const float*)d_in[1];
  const float* emb  = (const float*)d_in[2];
  const float* Wx0  = (const float*)d_in[3];
  const float* Wx1  = (const float*)d_in[4];
  const float* Wh   = (const float*)d_in[5];
  const float* bh   = (const float*)d_in[6];
  const float* Wout = (const float*)d_in[7];
  const float* bout = (const float*)d_in[8];
  float* out = (float*)d_out;

  char* ws = (char*)d_ws;
  size_t off = 0;
  auto alloc = [&](size_t bytes) -> void* {
    void* p = ws + off;
    off += (bytes + 255) & ~(size_t)255;
    return p;
  };
  unsigned* bar = (unsigned*)alloc(8192);
  u16* XBhi  = (u16*)alloc((size_t)ROWS_ * E_ * 2);
  u16* XBlo  = (u16*)alloc((size_t)ROWS_ * E_ * 2);
  u16* Wx0Th = (u16*)alloc((size_t)H_ * E_ * 2);
  u16* Wx0Tl = (u16*)alloc((size_t)H_ * E_ * 2);
  u16* Wx1Th = (u16*)alloc((size_t)H_ * H_ * 2);
  u16* Wx1Tl = (u16*)alloc((size_t)H_ * H_ * 2);
  u16* Wh0Th = (u16*)alloc((size_t)H_ * H_ * 2);
  u16* Wh0Tl = (u16*)alloc((size_t)H_ * H_ * 2);
  u16* Wh1Th = (u16*)alloc((size_t)H_ * H_ * 2);
  u16* Wh1Tl = (u16*)alloc((size_t)H_ * H_ * 2);
  u16* WoutT = (u16*)alloc((size_t)VP_ * H_ * 2);
  float* XP0 = (float*)alloc((size_t)ROWS_ * H_ * 4);
  float* XP1 = (float*)alloc((size_t)ROWS_ * H_ * 4);
  u16* H0hi  = (u16*)alloc((size_t)(SEQ_ + 1) * B_ * H_ * 2);
  u16* H0lo  = (u16*)alloc((size_t)(SEQ_ + 1) * B_ * H_ * 2);
  u16* H1hi  = (u16*)alloc((size_t)(SEQ_ + 1) * B_ * H_ * 2);
  u16* H1lo  = (u16*)alloc((size_t)(SEQ_ + 1) * B_ * H_ * 2);

  unsigned* flags = bar;
  unsigned* gen   = bar + 1024;

  hipMemsetAsync(bar, 0, 8192, stream);
  transpose_split<<<dim3(H_ / 32, E_ / 32), 256, 0, stream>>>(Wx0, Wx0Th, Wx0Tl, E_, H_, H_);
  transpose_split<<<dim3(H_ / 32, H_ / 32), 256, 0, stream>>>(Wx1, Wx1Th, Wx1Tl, H_, H_, H_);
  transpose_split<<<dim3(H_ / 32, H_ / 32), 256, 0, stream>>>(Wh,           Wh0Th, Wh0Tl, H_, H_, H_);
  transpose_split<<<dim3(H_ / 32, H_ / 32), 256, 0, stream>>>(Wh + H_ * H_, Wh1Th, Wh1Tl, H_, H_, H_);
  transpose_split<<<dim3(VP_ / 32, H_ / 32), 256, 0, stream>>>(Wout, WoutT, nullptr, H_, V_, VP_);
  gather_x<<<ROWS_ * E_ / 8 / 256, 256, 0, stream>>>(toks, emb, XBhi, XBlo);
  hid_cast<<<B_ * H_ / 256, 256, 0, stream>>>(hid0, H0hi, H0lo, H1hi, H1lo);

  // XP0 = x @ W_x0 + b0
  gemm_bf16<3><<<8 * 64, 256, 0, stream>>>(XBhi, XBlo, Wx0Th, Wx0Tl, bh, XP0,
                                           E_, H_, H_, 8, 64);
  // layer 0 recurrence (also writes final hidden layer 0)
  recur_layer<<<64, 256, 0, stream>>>(Wh0Th, Wh0Tl, XP0, H0hi, H0lo,
                                      out + LOGITS_, flags, gen);
  hipMemsetAsync(bar, 0, 8192, stream);
  // XP1 = H0 @ W_x1 + b1
  gemm_bf16<3><<<8 * 64, 256, 0, stream>>>(H0hi + B_ * H_, H0lo + B_ * H_,
                                           Wx1Th, Wx1Tl, bh + H_, XP1,
                                           H_, H_, H_, 8, 64);
  // layer 1 recurrence
  recur_layer<<<64, 256, 0, stream>>>(Wh1Th, Wh1Tl, XP1, H1hi, H1lo,
                                      out + LOGITS_ + B_ * H_, flags, gen);
  // logits = H1 @ W_out + b_out  (single-pass bf16)
  gemm_bf16<1><<<79 * 64, 256, 0, stream>>>(H1hi + B_ * H_, nullptr, WoutT, nullptr,
                                            bout, out, H_, V_, V_, 79, 64);
}

// Round 2
// 1741.415 us; speedup vs baseline: 2.8062x; 2.8062x over previous
//
#include <hip/hip_runtime.h>
#include <math.h>

// ---------------------------------------------------------------------------
// Stacked vanilla RNN (2 layers), SEQ=128 B=64 E=512 H=1024 V=10000.
//   prep:   transpose+split weights to bf16 hi/lo [n][k]; gather x; cast h0.
//   XP0 = x @ W_x0 + b0            (3-pass split-bf16 MFMA GEMM)
//   recur_fused: 130-stage software pipeline, 192 persistent WGs:
//     role L0 (64 WGs): h0[i]   = tanh(XP0[i] + h0[i-1] @ Wh0)
//     role P  (64 WGs): p[i-1]  = h0[i-1] @ Wx1 + b1
//     role L1 (64 WGs): h1[i-2] = tanh(p[i-2] + h1[i-3] @ Wh1)
//     one all-to-all flag barrier per stage; producers write through via
//     agent-scope atomic stores (no cache-invalidating fences).
//   logits = H1 @ W_out + b_out    (1-pass bf16 GEMM, supertiled)
// ---------------------------------------------------------------------------

typedef unsigned short u16;
typedef unsigned long long u64;
typedef __bf16 bf16x8 __attribute__((ext_vector_type(8)));
typedef float  f32x4  __attribute__((ext_vector_type(4)));
typedef unsigned int u32x4 __attribute__((ext_vector_type(4)));
typedef u16 u16x8 __attribute__((ext_vector_type(8)));

#define SEQ_ 128
#define B_   64
#define E_   512
#define H_   1024
#define V_   10000
#define VP_  10112
#define ROWS_ (SEQ_*B_)      // 8192
#define BH_  (B_*H_)         // 65536
#define LOGITS_ 81920000     // SEQ*B*V
#define NWG_ 192

__device__ __forceinline__ u16 f2bf(float f) {          // RNE f32 -> bf16
  unsigned u = __builtin_bit_cast(unsigned, f);
  u += 0x7fffu + ((u >> 16) & 1u);
  return (u16)(u >> 16);
}
__device__ __forceinline__ float bf2f(u16 h) {
  unsigned u = ((unsigned)h) << 16;
  return __builtin_bit_cast(float, u);
}
__device__ __forceinline__ void st64(void* p, u64 v) {   // write-through store
  __hip_atomic_store((u64*)p, v, __ATOMIC_RELAXED, __HIP_MEMORY_SCOPE_AGENT);
}
__device__ __forceinline__ u64 pk64(float a, float b) {
  return (u64)__builtin_bit_cast(unsigned, a) |
         ((u64)__builtin_bit_cast(unsigned, b) << 32);
}

// --------------------------- prep kernels ----------------------------------

__global__ __launch_bounds__(256)
void transpose_split(const float* __restrict__ in, u16* __restrict__ outHi,
                     u16* __restrict__ outLo, int K, int N, int NP)
{
  __shared__ float tile[32][33];
  const int n0 = blockIdx.x * 32, k0 = blockIdx.y * 32;
  const int x = threadIdx.x & 31;
  const int y = threadIdx.x >> 5;
  (void)NP;
#pragma unroll
  for (int i = 0; i < 4; ++i) {
    const int r = y * 4 + i;
    const int n = n0 + x;
    tile[r][x] = (n < N) ? in[(size_t)(k0 + r) * N + n] : 0.f;
  }
  __syncthreads();
#pragma unroll
  for (int i = 0; i < 4; ++i) {
    const int r = y * 4 + i;
    const int n = n0 + r;
    const int k = k0 + x;
    const float v = tile[x][r];
    const u16 hb = f2bf(v);
    outHi[(size_t)n * K + k] = hb;
    if (outLo) outLo[(size_t)n * K + k] = f2bf(v - bf2f(hb));
  }
}

__global__ __launch_bounds__(256)
void gather_x(const int* __restrict__ toks, const float* __restrict__ emb,
              u16* __restrict__ XBhi, u16* __restrict__ XBlo)
{
  const int tid = blockIdx.x * 256 + threadIdx.x;
  const int row = tid >> 6;
  const int c8 = (tid & 63) * 8;
  const int tok = toks[row];
  const float* e = emb + (size_t)tok * E_ + c8;
  u16x8 hv, lv;
#pragma unroll
  for (int j = 0; j < 8; ++j) {
    float f = e[j] * 22.627416997969522f;            // sqrt(512)
    u16 hb = f2bf(f);
    hv[j] = hb;
    lv[j] = f2bf(f - bf2f(hb));
  }
  *(u16x8*)(XBhi + (size_t)row * E_ + c8) = hv;
  *(u16x8*)(XBlo + (size_t)row * E_ + c8) = lv;
}

__global__ __launch_bounds__(256)
void hid_cast(const float* __restrict__ h, u16* H0hi, u16* H0lo, u16* H1hi, u16* H1lo)
{
  const int tid = blockIdx.x * 256 + threadIdx.x;
  float v0 = h[tid], v1 = h[BH_ + tid];
  u16 a = f2bf(v0); H0hi[tid] = a; H0lo[tid] = f2bf(v0 - bf2f(a));
  u16 b = f2bf(v1); H1hi[tid] = b; H1lo[tid] = f2bf(v1 - bf2f(b));
}

// --------------------------- generic MFMA GEMM -----------------------------
template<int NPASS>
__global__ __launch_bounds__(256)
void gemm_bf16(const u16* __restrict__ Ahi, const u16* __restrict__ Alo,
               const u16* __restrict__ Bhi, const u16* __restrict__ Blo,
               const float* __restrict__ bias, float* __restrict__ C,
               int K, int Nreal, int ldc, int nbx, int nby)
{
  constexpr int LDT = 40;
  __shared__ u16 lds[(NPASS == 3 ? 4 : 2) * 128 * LDT];
  u16* As  = lds;
  u16* Bs  = lds + 128 * LDT;
  u16* As2 = (NPASS == 3) ? (lds + 2 * 128 * LDT) : lds;
  u16* Bs2 = (NPASS == 3) ? (lds + 3 * 128 * LDT) : lds;

  const int S = 8;
  int bid  = blockIdx.x;
  int scol = bid / (S * nby);
  int rem  = bid - scol * (S * nby);
  int w    = nbx - scol * S; if (w > S) w = S;
  int bx   = scol * S + rem % w;
  int by   = rem / w;
  const int m0 = by * 128, n0 = bx * 128;

  const int tid  = threadIdx.x;
  const int wave = tid >> 6, lane = tid & 63;
  const int wm = (wave & 1) * 64, wn = (wave >> 1) * 64;
  const int lrow = lane & 15, lk = (lane >> 4) * 8;

  f32x4 acc[4][4] = {};

  const int kTiles = K >> 5;
  for (int kt = 0; kt < kTiles; ++kt) {
    const int k0 = kt << 5;
    __syncthreads();
#pragma unroll
    for (int c = tid; c < 512; c += 256) {
      const int row = c >> 2, kq = c & 3;
      const int l = row * LDT + kq * 8;
      *(u32x4*)(As + l) = *(const u32x4*)(Ahi + (size_t)(m0 + row) * K + k0 + kq * 8);
      *(u32x4*)(Bs + l) = *(const u32x4*)(Bhi + (size_t)(n0 + row) * K + k0 + kq * 8);
      if constexpr (NPASS == 3) {
        *(u32x4*)(As2 + l) = *(const u32x4*)(Alo + (size_t)(m0 + row) * K + k0 + kq * 8);
        *(u32x4*)(Bs2 + l) = *(const u32x4*)(Blo + (size_t)(n0 + row) * K + k0 + kq * 8);
      }
    }
    __syncthreads();
    bf16x8 a[4], b[4];
#pragma unroll
    for (int i = 0; i < 4; ++i) {
      a[i] = *(const bf16x8*)(As + (wm + i * 16 + lrow) * LDT + lk);
      b[i] = *(const bf16x8*)(Bs + (wn + i * 16 + lrow) * LDT + lk);
    }
    if constexpr (NPASS == 3) {
      bf16x8 a2[4], b2[4];
#pragma unroll
      for (int i = 0; i < 4; ++i) {
        a2[i] = *(const bf16x8*)(As2 + (wm + i * 16 + lrow) * LDT + lk);
        b2[i] = *(const bf16x8*)(Bs2 + (wn + i * 16 + lrow) * LDT + lk);
      }
#pragma unroll
      for (int mi = 0; mi < 4; ++mi)
#pragma unroll
        for (int ni = 0; ni < 4; ++ni) {
          acc[mi][ni] = __builtin_amdgcn_mfma_f32_16x16x32_bf16(a[mi],  b[ni],  acc[mi][ni], 0, 0, 0);
          acc[mi][ni] = __builtin_amdgcn_mfma_f32_16x16x32_bf16(a[mi],  b2[ni], acc[mi][ni], 0, 0, 0);
          acc[mi][ni] = __builtin_amdgcn_mfma_f32_16x16x32_bf16(a2[mi], b[ni],  acc[mi][ni], 0, 0, 0);
        }
    } else {
#pragma unroll
      for (int mi = 0; mi < 4; ++mi)
#pragma unroll
        for (int ni = 0; ni < 4; ++ni)
          acc[mi][ni] = __builtin_amdgcn_mfma_f32_16x16x32_bf16(a[mi], b[ni], acc[mi][ni], 0, 0, 0);
    }
  }
#pragma unroll
  for (int mi = 0; mi < 4; ++mi)
#pragma unroll
    for (int ni = 0; ni < 4; ++ni)
#pragma unroll
      for (int r = 0; r < 4; ++r) {
        const int row = m0 + wm + mi * 16 + (lane >> 4) * 4 + r;
        const int col = n0 + wn + ni * 16 + lrow;
        if (col < Nreal) {
          float v = acc[mi][ni][r];
          if (bias) v += bias[col];
          C[(size_t)row * ldc + col] = v;
        }
      }
}

// --------------------------- all-to-all grid barrier ------------------------
// Producers already drained their write-through stores (vmcnt(0)); each WG
// posts flags[wg]=my; every WG's wave0 scans all 192 flags. No fences: the
// payload stores are agent-scope write-through, and consumers' caches cannot
// hold a this-run stale copy of any slot (each slot address written once and
// read only after its flag).
__device__ __forceinline__ void gbar192(unsigned* flags, unsigned my)
{
  asm volatile("s_waitcnt vmcnt(0)" ::: "memory");
  __syncthreads();
  if (threadIdx.x == 0)
    __hip_atomic_store(flags + blockIdx.x * 16u, my, __ATOMIC_RELAXED,
                       __HIP_MEMORY_SCOPE_AGENT);
  if (threadIdx.x < 64) {
    const int l = threadIdx.x;
    bool ok0 = false, ok1 = false, ok2 = false;
    for (;;) {
      if (!ok0) ok0 = __hip_atomic_load(flags + l * 16,         __ATOMIC_RELAXED, __HIP_MEMORY_SCOPE_AGENT) >= my;
      if (!ok1) ok1 = __hip_atomic_load(flags + (l + 64) * 16,  __ATOMIC_RELAXED, __HIP_MEMORY_SCOPE_AGENT) >= my;
      if (!ok2) ok2 = __hip_atomic_load(flags + (l + 128) * 16, __ATOMIC_RELAXED, __HIP_MEMORY_SCOPE_AGENT) >= my;
      if (__all(ok0 && ok1 && ok2)) break;
      __builtin_amdgcn_s_sleep(2);
    }
  }
  __syncthreads();
}

// --------------------------- fused recurrence ------------------------------
// 192 WGs x 256 thr (1 WG/CU). WG role: 0=L0, 1=P, 2=L1; within role,
// idx = bg*32... actually bg = idx>>5 (batch group of 32), cg = idx&31
// (32-col strip). 4 waves = 2 batch-subgroups x 2 col-subgroups of 16.
// Weight strip (hi+lo) staged once in XOR-swizzled LDS (128 KB).
// MFMA with swapped operands: D[col-in-tile][batch], so each lane owns
// 4 consecutive output columns of one batch row -> packed 8B stores.
__global__ __launch_bounds__(256, 1)
void recur_fused(const u16* __restrict__ Wh0h, const u16* __restrict__ Wh0l,
                 const u16* __restrict__ Wx1h, const u16* __restrict__ Wx1l,
                 const u16* __restrict__ Wh1h, const u16* __restrict__ Wh1l,
                 const float* __restrict__ XP0, const float* __restrict__ b1,
                 float* __restrict__ Pbuf,
                 u16* __restrict__ H0hi, u16* __restrict__ H0lo,
                 u16* __restrict__ H1hi, u16* __restrict__ H1lo,
                 float* __restrict__ final0, float* __restrict__ final1,
                 unsigned* __restrict__ flags)
{
  __shared__ u16 bsm[2 * 32 * 1024];   // 128 KB: [hi/lo][col][k], XOR-swizzled

  const int wg   = blockIdx.x;
  const int role = (wg < 64) ? 0 : (wg < 128) ? 1 : 2;
  const int idx  = wg & 63;
  const int bg   = idx >> 5, cg = idx & 31;

  const u16* Bhi = (role == 0) ? Wh0h : (role == 1) ? Wx1h : Wh1h;
  const u16* Blo = (role == 0) ? Wh0l : (role == 1) ? Wx1l : Wh1l;

  const int tid  = threadIdx.x;
  const int wv   = tid >> 6, lane = tid & 63;
  const int wbg  = wv >> 1, wcg = wv & 1;
  const int lb   = lane & 15;
  const int lk8  = (lane >> 4) * 8;

  // stage weight strip (hi then lo) into LDS, swizzled
  for (int c = tid; c < 8192; c += 256) {
    const int p   = c >> 12;
    const int cc  = c & 4095;
    const int col = cc >> 7;
    const int k8  = (cc & 127) * 8;
    u32x4 v = *(const u32x4*)((p ? Blo : Bhi) + (size_t)(cg * 32 + col) * H_ + k8);
    *(u32x4*)(bsm + p * 32768 + col * 1024 + (k8 ^ ((col & 7) << 3))) = v;
  }
  __syncthreads();

  const int batch = bg * 32 + wbg * 16 + lb;
  const int c0    = cg * 32 + wcg * 16 + (lk8 >> 1);   // (lane>>4)*4
  const int colL  = wcg * 16 + lb;
  const int xorv  = (colL & 7) << 3;
  const u16* bsp  = bsm + colL * 1024;
  const size_t aoff = (size_t)batch * H_ + lk8;

  for (int i = 0; i < 130; ++i) {
    bool active; int t;
    if (role == 0)      { active = (i < 128);           t = i;     }
    else if (role == 1) { active = (i >= 1 && i < 129); t = i - 1; }
    else                { active = (i >= 2);            t = i - 2; }

    if (active) {
      const u16 *Ahi, *Alo;
      const float* initp;
      if (role == 0) {
        Ahi = H0hi + (size_t)t * BH_;  Alo = H0lo + (size_t)t * BH_;
        initp = XP0 + (size_t)t * BH_ + (size_t)batch * H_ + c0;
      } else if (role == 1) {
        Ahi = H0hi + (size_t)(t + 1) * BH_;  Alo = H0lo + (size_t)(t + 1) * BH_;
        initp = b1 + c0;
      } else {
        Ahi = H1hi + (size_t)t * BH_;  Alo = H1lo + (size_t)t * BH_;
        initp = Pbuf + (size_t)t * BH_ + (size_t)batch * H_ + c0;
      }

      f32x4 acc0 = *(const f32x4*)initp;
      f32x4 acc1 = {0.f, 0.f, 0.f, 0.f};
#pragma unroll
      for (int kc = 0; kc < 32; ++kc) {
        bf16x8 ah = *(const bf16x8*)(Ahi + aoff + kc * 32);
        bf16x8 al = *(const bf16x8*)(Alo + aoff + kc * 32);
        bf16x8 bh = *(const bf16x8*)(bsp + ((kc * 32 + lk8) ^ xorv));
        bf16x8 bl = *(const bf16x8*)(bsp + 32768 + ((kc * 32 + lk8) ^ xorv));
        if (kc & 1) {
          acc1 = __builtin_amdgcn_mfma_f32_16x16x32_bf16(bh, ah, acc1, 0, 0, 0);
          acc1 = __builtin_amdgcn_mfma_f32_16x16x32_bf16(bl, ah, acc1, 0, 0, 0);
          acc1 = __builtin_amdgcn_mfma_f32_16x16x32_bf16(bh, al, acc1, 0, 0, 0);
        } else {
          acc0 = __builtin_amdgcn_mfma_f32_16x16x32_bf16(bh, ah, acc0, 0, 0, 0);
          acc0 = __builtin_amdgcn_mfma_f32_16x16x32_bf16(bl, ah, acc0, 0, 0, 0);
          acc0 = __builtin_amdgcn_mfma_f32_16x16x32_bf16(bh, al, acc0, 0, 0, 0);
        }
      }
      acc0 = acc0 + acc1;

      if (role == 1) {
        float* op = Pbuf + (size_t)t * BH_ + (size_t)batch * H_ + c0;
        st64(op,     pk64(acc0[0], acc0[1]));
        st64(op + 2, pk64(acc0[2], acc0[3]));
      } else {
        float hv[4];
        u64 whi = 0, wlo = 0;
#pragma unroll
        for (int r = 0; r < 4; ++r) {
          float v = tanhf(acc0[r]);
          u16 hb = f2bf(v);
          u16 lo = f2bf(v - bf2f(hb));
          whi |= (u64)hb << (16 * r);
          wlo |= (u64)lo << (16 * r);
          hv[r] = v;
        }
        u16* OH = (role == 0 ? H0hi : H1hi) + (size_t)(t + 1) * BH_ + (size_t)batch * H_ + c0;
        u16* OL = (role == 0 ? H0lo : H1lo) + (size_t)(t + 1) * BH_ + (size_t)batch * H_ + c0;
        st64(OH, whi);
        st64(OL, wlo);
        if (t == SEQ_ - 1) {
          float* fp = (role == 0 ? final0 : final1) + (size_t)batch * H_ + c0;
          st64(fp,     pk64(hv[0], hv[1]));
          st64(fp + 2, pk64(hv[2], hv[3]));
        }
      }
    }
    if (i < 129) gbar192(flags, (unsigned)(i + 1));
  }
}

// --------------------------- launch ----------------------------------------
extern "C" void kernel_launch(void* const* d_in, const int* in_sizes, int n_in,
                              void* d_out, int out_size, void* d_ws, size_t ws_size,
                              hipStream_t stream)
{
  (void)in_sizes; (void)n_in; (void)out_size; (void)ws_size; // needs ~186 MB ws
  const int*   toks = (const int*)d_in[0];
  const float* hid0 = (const float*)d_in[1];
  const float* emb  = (const float*)d_in[2];
  const float* Wx0  = (const float*)d_in[3];
  const float* Wx1  = (const float*)d_in[4];
  const float* Wh   = (const float*)d_in[5];
  const float* bh   = (const float*)d_in[6];
  const float* Wout = (const float*)d_in[7];
  const float* bout = (const float*)d_in[8];
  float* out = (float*)d_out;

  char* ws = (char*)d_ws;
  size_t off = 0;
  auto alloc = [&](size_t bytes) -> void* {
    void* p = ws + off;
    off += (bytes + 255) & ~(size_t)255;
    return p;
  };
  unsigned* flags = (unsigned*)alloc(16384);
  u16* XBhi  = (u16*)alloc((size_t)ROWS_ * E_ * 2);
  u16* XBlo  = (u16*)alloc((size_t)ROWS_ * E_ * 2);
  u16* Wx0Th = (u16*)alloc((size_t)H_ * E_ * 2);
  u16* Wx0Tl = (u16*)alloc((size_t)H_ * E_ * 2);
  u16* Wx1Th = (u16*)alloc((size_t)H_ * H_ * 2);
  u16* Wx1Tl = (u16*)alloc((size_t)H_ * H_ * 2);
  u16* Wh0Th = (u16*)alloc((size_t)H_ * H_ * 2);
  u16* Wh0Tl = (u16*)alloc((size_t)H_ * H_ * 2);
  u16* Wh1Th = (u16*)alloc((size_t)H_ * H_ * 2);
  u16* Wh1Tl = (u16*)alloc((size_t)H_ * H_ * 2);
  u16* WoutT = (u16*)alloc((size_t)VP_ * H_ * 2);
  float* XP0 = (float*)alloc((size_t)ROWS_ * H_ * 4);
  float* Pbuf= (float*)alloc((size_t)SEQ_ * BH_ * 4);
  u16* H0hi  = (u16*)alloc((size_t)(SEQ_ + 1) * BH_ * 2);
  u16* H0lo  = (u16*)alloc((size_t)(SEQ_ + 1) * BH_ * 2);
  u16* H1hi  = (u16*)alloc((size_t)(SEQ_ + 1) * BH_ * 2);
  u16* H1lo  = (u16*)alloc((size_t)(SEQ_ + 1) * BH_ * 2);

  hipMemsetAsync(flags, 0, 16384, stream);
  transpose_split<<<dim3(H_ / 32, E_ / 32), 256, 0, stream>>>(Wx0, Wx0Th, Wx0Tl, E_, H_, H_);
  transpose_split<<<dim3(H_ / 32, H_ / 32), 256, 0, stream>>>(Wx1, Wx1Th, Wx1Tl, H_, H_, H_);
  transpose_split<<<dim3(H_ / 32, H_ / 32), 256, 0, stream>>>(Wh,           Wh0Th, Wh0Tl, H_, H_, H_);
  transpose_split<<<dim3(H_ / 32, H_ / 32), 256, 0, stream>>>(Wh + H_ * H_, Wh1Th, Wh1Tl, H_, H_, H_);
  transpose_split<<<dim3(VP_ / 32, H_ / 32), 256, 0, stream>>>(Wout, WoutT, nullptr, H_, V_, VP_);
  gather_x<<<ROWS_ * E_ / 8 / 256, 256, 0, stream>>>(toks, emb, XBhi, XBlo);
  hid_cast<<<BH_ / 256, 256, 0, stream>>>(hid0, H0hi, H0lo, H1hi, H1lo);

  // XP0 = x @ W_x0 + b0
  gemm_bf16<3><<<8 * 64, 256, 0, stream>>>(XBhi, XBlo, Wx0Th, Wx0Tl, bh, XP0,
                                           E_, H_, H_, 8, 64);
  // fused pipelined recurrence (both layers + Wx1 projection)
  recur_fused<<<NWG_, 256, 0, stream>>>(Wh0Th, Wh0Tl, Wx1Th, Wx1Tl, Wh1Th, Wh1Tl,
                                        XP0, bh + H_, Pbuf,
                                        H0hi, H0lo, H1hi, H1lo,
                                        out + LOGITS_, out + LOGITS_ + BH_, flags);
  // logits = H1 @ W_out + b_out
  gemm_bf16<1><<<79 * 64, 256, 0, stream>>>(H1hi + BH_, nullptr, WoutT, nullptr,
                                            bout, out, H_, V_, V_, 79, 64);
}